// Round 1
// 520.475 us; speedup vs baseline: 1.5119x; 1.5119x over previous
//
#include <hip/hip_runtime.h>

#define Dn 200
#define Cn 8
#define Gn 10000
#define Vn 20000
#define VGn 50000
#define GLn 500
#define EPSf 1e-8f
#define ZSPLIT 8
#define CHUNK (Dn / ZSPLIT)   // 25 donors per block

// Stirling series, accurate for y >= 8
__device__ __forceinline__ float stirling_lg(float y) {
    float ly  = __logf(y);
    float iv  = __builtin_amdgcn_rcpf(y);
    float iv2 = iv * iv;
    float ser = iv * (0.08333333333333f + iv2 * (-0.00277777777778f + iv2 * 0.00079365079365f));
    return fmaf(y - 0.5f, ly, -y) + 0.91893853320467274f + ser;
}

// lgamma(x) for ANY x > 0: shift by 8, then Stirling.
// Product of 8 terms folded into 5 ops via (x+k)(x+7-k) = q + k(7-k), q = x(x+7).
__device__ __forceinline__ float lgamma_shift8(float x) {
    const float q = x * (x + 7.0f);
    const float p = (q * (q + 6.0f)) * ((q + 10.0f) * (q + 12.0f));
    return stirling_lg(x + 8.0f) - __logf(p);
}

__global__ __launch_bounds__(256, 4) void elbo_kernel(
    const float* __restrict__ fc_log,
    const float* __restrict__ genotypes,
    const float* __restrict__ obs,
    const float* __restrict__ lib,
    const float* __restrict__ baseline_log,
    const float* __restrict__ dispersion_log,
    const int* __restrict__ v2g,
    const int* __restrict__ lv_sel,
    const int* __restrict__ v2lg,
    float* __restrict__ out)
{
    __shared__ float s_ltab[128];        // lgamma(1+n)
    __shared__ float s_loglib[Dn * Cn];  // log(lib[d][c]) for all d,c

    const int tid = threadIdx.x;
    int vg = blockIdx.x * 256 + tid;
    const bool active = (vg < VGn);
    if (!active) vg = VGn - 1;

    // ---- block preamble ----
    if (tid < 128) s_ltab[tid] = lgamma_shift8(1.0f + (float)tid);
    for (int idx = tid; idx < Dn * Cn; idx += 256)
        s_loglib[idx] = __logf(lib[idx]);

    // ---- per-thread (vg) params: ONE set of index/gene gathers for all 8 c ----
    const int lv   = lv_sel[vg];
    const int lg   = v2lg[vg];
    const int gene = v2g[vg];

    float fc[Cn], bl[Cn], r_[Cn], K_[Cn], r2e[Cn];
    #pragma unroll
    for (int c = 0; c < Cn; ++c) {
        fc[c] = fc_log[c * VGn + vg];
        bl[c] = baseline_log[c * Gn + gene];
        const float dl   = dispersion_log[c * Gn + gene];
        const float disp = fminf(__expf(dl), 20.0f);
        const float r    = 1.0f / disp;
        r_[c]  = r;
        K_[c]  = lgamma_shift8(r) - r * __logf(r + EPSf);
        r2e[c] = r + 2.0f * EPSf;
    }
    __syncthreads();

    // ---- main loop over this block's donor chunk ----
    const int d0 = blockIdx.z * CHUNK;
    const float* gp  = genotypes + (size_t)d0 * Vn + lv;
    const float* op  = obs + (size_t)d0 * (Cn * GLn) + lg;
    float*       wp  = out + (size_t)d0 * (Cn * VGn) + vg;
    const float* llp = s_loglib + d0 * Cn;

    #pragma unroll 2
    for (int i = 0; i < CHUNK; ++i) {
        const float g = *gp; gp += Vn;          // ONE genotype gather per d (was 8)

        float val[Cn];
        #pragma unroll
        for (int c = 0; c < Cn; ++c) val[c] = op[c * GLn];
        op += Cn * GLn;

        #pragma unroll
        for (int c = 0; c < Cn; ++c) {
            const float value = val[c];
            const float s  = fmaf(g, fc[c], bl[c] + llp[c]);
            const float mu = __expf(s);
            const float L  = __logf(r2e[c] + mu);
            const float rv = r_[c] + value;

            int vi = (int)value;
            vi = vi < 0 ? 0 : (vi > 127 ? 127 : vi);

            const float lgrv = lgamma_shift8(rv);   // branchless, no per-thread table
            const float e = fmaf(rv, L, K_[c]) - value * s + s_ltab[vi] - lgrv;
            if (active) wp[c * VGn] = e;
        }
        llp += Cn;
        wp  += Cn * VGn;
    }
}

extern "C" void kernel_launch(void* const* d_in, const int* in_sizes, int n_in,
                              void* d_out, int out_size, void* d_ws, size_t ws_size,
                              hipStream_t stream) {
    const float* fc_log         = (const float*)d_in[0];
    const float* genotypes      = (const float*)d_in[1];
    const float* obs            = (const float*)d_in[2];
    const float* lib            = (const float*)d_in[3];
    const float* baseline_log   = (const float*)d_in[4];
    const float* dispersion_log = (const float*)d_in[5];
    const int* v2g    = (const int*)d_in[6];
    const int* lv_sel = (const int*)d_in[7];
    const int* v2lg   = (const int*)d_in[8];
    float* out = (float*)d_out;

    dim3 grid((VGn + 255) / 256, 1, ZSPLIT);
    elbo_kernel<<<grid, 256, 0, stream>>>(fc_log, genotypes, obs, lib,
                                          baseline_log, dispersion_log,
                                          v2g, lv_sel, v2lg, out);
}